// Round 10
// baseline (162.915 us; speedup 1.0000x reference)
//
#include <hip/hip_runtime.h>
#include <hip/hip_bf16.h>
#include <stdint.h>

// Problem constants (fixed by reference): B=4,S=512 -> 2048 tokens, D=512, H=2048, E=8
#define D_DIM 512
#define H_DIM 2048
#define E_NUM 8
#define TM 64            // row-tile (padding granularity)
#define CAP 2560         // 2048 tokens + worst-case per-expert padding
#define MAXRT 6          // max row-tiles per expert (384 rows; ne~256±15, 8.5 sigma)

typedef __attribute__((ext_vector_type(8))) short short8;
typedef __attribute__((ext_vector_type(4))) float floatx4;

union Pack4 { short4 u; __hip_bfloat16 h[4]; };
union Pack8 { short8 s; __hip_bfloat16 h[8]; };

// ---------------------------------------------------------------------------
// 1) Token binning. meta[0..7]=padded offset, [8..15]=ne, [16..23]=ntiles, [24]=total
// gidx[CAP]: token index per sorted slot, -1 for padding slots.
__global__ __launch_bounds__(256) void bin_kernel(
    const int* __restrict__ orig, const int* __restrict__ hmap,
    int* __restrict__ gidx, int* __restrict__ meta, int ntok)
{
    __shared__ int cnt[E_NUM];
    __shared__ int cur[E_NUM];
    int tid = threadIdx.x;
    if (tid < E_NUM) cnt[tid] = 0;
    __syncthreads();
    for (int t = tid; t < ntok; t += 256) {
        int b = hmap[orig[t]];
        atomicAdd(&cnt[b], 1);
    }
    __syncthreads();
    if (tid == 0) {
        int off = 0;
        for (int e = 0; e < E_NUM; e++) {
            int ne = cnt[e];
            int nt = (ne + TM - 1) / TM;
            meta[e] = off; meta[8 + e] = ne; meta[16 + e] = nt;
            cur[e] = off;
            off += nt * TM;
        }
        meta[24] = off;
    }
    __syncthreads();
    for (int g = tid; g < CAP; g += 256) gidx[g] = -1;   // pads
    __syncthreads();
    for (int t = tid; t < ntok; t += 256) {
        int b = hmap[orig[t]];
        int p = atomicAdd(&cur[b], 1);
        gidx[p] = t;
    }
}

// ---------------------------------------------------------------------------
// 2) Expert-column MoE GEMM (R9-champion structure; register round-trip
// staging so prefetch loads fly across the barrier pair).
//   IND=true  (gemm1): A sourced DIRECTLY from x (fp32) via gidx indirection,
//                      fp32->bf16 convert inside WRITEA; pad rows -> 0.
//   IND=false (gemm2): A = dense bf16 [CAP, ASTRIDE] (Hb).
//   W [E][KTOT][WN] fp32 (fused cvt+transpose into swizzled Bs)
//   RELU: OutBf = bf16(relu(acc + bias));  else OutP[ks][CAP][WN] bf16 partials
// LDS: As [384 x 64k] bf16 48 KB (phys chunk c=(row*8+q): byte c*16 holds
//      src k-bytes (q*16)^((row&7)*16) -> conflict-free b128 reads/writes),
//      Bs [64n x 64k] bf16 8 KB (phys(n,kb)=n*128+(kb^(((n>>2)&7)*16)))
template <int WN, int ASTRIDE, int KTOT, int KS, bool RELU, bool IND>
__global__ __launch_bounds__(256) void moe_gemm_kernel(
    const __hip_bfloat16* __restrict__ A,   // IND=false path
    const float* __restrict__ Xf,           // IND=true path
    const int* __restrict__ gidx,           // IND=true path
    const float* __restrict__ W,
    const float* __restrict__ bias,
    __hip_bfloat16* __restrict__ OutBf,     // RELU: full output
    __hip_bfloat16* __restrict__ OutP,      // !RELU: bf16 split-K partials
    const int* __restrict__ meta)
{
    constexpr int KLEN = KTOT / KS;           // 512 in both instantiations
    constexpr int NI = KLEN / 64;             // 8 k-iterations
    constexpr int AJ = MAXRT * 64 * 8 / 256;  // 12 A-chunks (16B) per thread max
    const int e = blockIdx.z;
    const int n0 = blockIdx.x * 64;
    const int ks = blockIdx.y;
    const int kbase = ks * KLEN;

    int nt = meta[16 + e];
    if (nt > MAXRT) nt = MAXRT;
    const int row0 = meta[e];
    const int rows8 = nt * 64 * 8;            // active 16B chunks in A stage

    __shared__ __align__(16) __hip_bfloat16 As[384 * 64];   // 48 KB
    __shared__ __align__(16) __hip_bfloat16 Bs[64 * 64];    // 8 KB

    const int tid = threadIdx.x;
    const int lane = tid & 63, w = tid >> 6;
    const int quad = lane >> 4, l16 = lane & 15;
    const int wr = w >> 1, wc = w & 1;        // 2x2 wave grid per 64x64 tile
    const int kq = tid >> 4;                  // B staging: 4 k-rows
    const int nb = tid & 15;                  // B staging: 4 n-cols

    const __hip_bfloat16* Ab = A + (size_t)row0 * ASTRIDE + kbase;
    const float* Wb = W + ((size_t)e * KTOT + kbase) * WN + n0;

    floatx4 acc[MAXRT][2][2] = {};
    short8 ar[IND ? 1 : AJ];                  // bf16 A prefetch (gemm2)
    float4 arf[IND ? AJ : 1][2];              // fp32 A prefetch (gemm1)
    const float* tp[IND ? AJ : 1];            // per-chunk row base (gemm1)
    int koff[IND ? AJ : 1];                   // per-chunk swizzled k element
    float4 br[4];                             // B prefetch registers

    if constexpr (IND) {
#pragma unroll
        for (int j = 0; j < AJ; j++) {
            int c = tid + j * 256;
            int row = c >> 3;
            int kk = ((c & 7) * 16) ^ ((row & 7) * 16);   // bytes in bf16 layout
            koff[j] = kk >> 1;                            // element offset
            tp[j] = nullptr;
            if (c < rows8) {
                int tr = gidx[row0 + row];
                if (tr >= 0) tp[j] = Xf + (size_t)tr * D_DIM + kbase;
            }
        }
    }

#define LOADA(k0) do {                                                        \
    if constexpr (IND) {                                                      \
        _Pragma("unroll")                                                     \
        for (int j = 0; j < AJ; j++) {                                        \
            if (tp[j]) {                                                      \
                arf[j][0] = *(const float4*)(tp[j] + (k0) + koff[j]);         \
                arf[j][1] = *(const float4*)(tp[j] + (k0) + koff[j] + 4);     \
            } else {                                                          \
                arf[j][0] = float4{0.f, 0.f, 0.f, 0.f};                       \
                arf[j][1] = float4{0.f, 0.f, 0.f, 0.f};                       \
            }                                                                 \
        }                                                                     \
    } else {                                                                  \
        _Pragma("unroll")                                                     \
        for (int j = 0; j < AJ; j++) {                                        \
            int c = tid + j * 256;                                            \
            if (c < rows8) {                                                  \
                int row = c >> 3;                                             \
                int kk = ((c & 7) * 16) ^ ((row & 7) * 16);                   \
                ar[j] = *(const short8*)(Ab + (size_t)row * ASTRIDE + (k0) + (kk >> 1)); \
            }                                                                 \
        }                                                                     \
    }                                                                         \
} while (0)

#define WRITEA() do {                                                         \
    if constexpr (IND) {                                                      \
        _Pragma("unroll")                                                     \
        for (int j = 0; j < AJ; j++) {                                        \
            int c = tid + j * 256;                                            \
            if (c < rows8) {                                                  \
                Pack8 pk;                                                     \
                _Pragma("unroll")                                             \
                for (int r = 0; r < 4; r++) {                                 \
                    pk.h[r] = __float2bfloat16(reinterpret_cast<const float*>(&arf[j][0])[r]); \
                    pk.h[4 + r] = __float2bfloat16(reinterpret_cast<const float*>(&arf[j][1])[r]); \
                }                                                             \
                *(short8*)((char*)As + c * 16) = pk.s;                        \
            }                                                                 \
        }                                                                     \
    } else {                                                                  \
        _Pragma("unroll")                                                     \
        for (int j = 0; j < AJ; j++) {                                        \
            int c = tid + j * 256;                                            \
            if (c < rows8)                                                    \
                *(short8*)((char*)As + c * 16) = ar[j];                       \
        }                                                                     \
    }                                                                         \
} while (0)

#define LOADB(k0) do {                                                        \
    _Pragma("unroll")                                                         \
    for (int r = 0; r < 4; r++)                                               \
        br[r] = *(const float4*)(Wb + (size_t)((k0) + kq * 4 + r) * WN + nb * 4); \
} while (0)

#define WRITEB() do {                                                         \
    _Pragma("unroll")                                                         \
    for (int j = 0; j < 4; j++) {                                             \
        int n = nb * 4 + j;                                                   \
        Pack4 pk;                                                             \
        _Pragma("unroll")                                                     \
        for (int r = 0; r < 4; r++)                                           \
            pk.h[r] = __float2bfloat16(reinterpret_cast<const float*>(&br[r])[j]); \
        *(short4*)((char*)Bs + n * 128 + ((kq * 8) ^ (((n >> 2) & 7) * 16))) = pk.u; \
    }                                                                         \
} while (0)

    LOADA(0);
    LOADB(0);

    for (int i = 0; i < NI; i++) {
        __syncthreads();    // prior iter's LDS reads complete
        WRITEA();           // vmcnt wait for loads issued one iter ago lands here
        WRITEB();
        __syncthreads();
        if (i + 1 < NI) {   // issue next-iter loads; they fly across the barriers
            LOADA((i + 1) * 64);
            LOADB((i + 1) * 64);
        }
#pragma unroll
        for (int kf = 0; kf < 2; kf++) {
            int kb = kf * 64 + quad * 16;
            short8 b[2];
#pragma unroll
            for (int ni = 0; ni < 2; ni++) {
                int n = wc * 32 + ni * 16 + l16;
                b[ni] = *(const short8*)((char*)Bs + n * 128 + (kb ^ (((n >> 2) & 7) * 16)));
            }
#pragma unroll
            for (int rt = 0; rt < MAXRT; rt++) {
                if (rt < nt) {
                    short8 a[2];
#pragma unroll
                    for (int mi = 0; mi < 2; mi++) {
                        int row = rt * 64 + wr * 32 + mi * 16 + l16;
                        a[mi] = *(const short8*)((char*)As + row * 128 + (kb ^ ((row & 7) * 16)));
                    }
#pragma unroll
                    for (int mi = 0; mi < 2; mi++)
#pragma unroll
                        for (int ni = 0; ni < 2; ni++)
                            acc[rt][mi][ni] = __builtin_amdgcn_mfma_f32_16x16x32_bf16(
                                a[mi], b[ni], acc[rt][mi][ni], 0, 0, 0);
                }
            }
        }
    }

    // Epilogue. C/D layout (m89-verified): col = lane&15, row = (lane>>4)*4 + reg
#pragma unroll
    for (int rt = 0; rt < MAXRT; rt++) {
        if (rt >= nt) break;
#pragma unroll
        for (int ni = 0; ni < 2; ni++) {
            int col = n0 + wc * 32 + ni * 16 + l16;
            float bv = RELU ? bias[e * WN + col] : 0.f;
#pragma unroll
            for (int mi = 0; mi < 2; mi++) {
#pragma unroll
                for (int r = 0; r < 4; r++) {
                    int grow = row0 + rt * 64 + wr * 32 + mi * 16 + quad * 4 + r;
                    float v = acc[rt][mi][ni][r] + bv;
                    if constexpr (RELU) {
                        v = v > 0.f ? v : 0.f;
                        OutBf[(size_t)grow * WN + col] = __float2bfloat16(v);
                    } else {
                        OutP[((size_t)ks * CAP + grow) * WN + col] = __float2bfloat16(v);
                    }
                }
            }
        }
    }
#undef LOADA
#undef WRITEA
#undef LOADB
#undef WRITEB
}

// ---------------------------------------------------------------------------
// 3) Residual + b2 + 4-way bf16 split-K sum + LayerNorm, scatter to token order.
__global__ __launch_bounds__(128) void ln_kernel(
    const float* __restrict__ x, const __hip_bfloat16* __restrict__ Yp,
    const float* __restrict__ b2,
    const float* __restrict__ gamma, const float* __restrict__ beta,
    const int* __restrict__ gidx, const int* __restrict__ meta,
    float* __restrict__ out)
{
    int g = blockIdx.x;
    int e = -1;
#pragma unroll
    for (int i = 0; i < E_NUM; i++) {
        int p = meta[i], ne = meta[8 + i];
        if (g >= p && g - p < ne) e = i;
    }
    if (e < 0) return;   // padding row or beyond total
    int t = gidx[g];
    int tid = threadIdx.x;

    float4 xv = ((const float4*)(x + (size_t)t * D_DIM))[tid];
    float4 bb = ((const float4*)(b2 + (size_t)e * D_DIM))[tid];
    float z0 = xv.x + bb.x, z1 = xv.y + bb.y, z2 = xv.z + bb.z, z3 = xv.w + bb.w;
#pragma unroll
    for (int s4 = 0; s4 < 4; s4++) {
        union { short4 u; __hip_bfloat16 h[4]; } yv;
        yv.u = ((const short4*)(Yp + (size_t)(s4 * CAP + g) * D_DIM))[tid];
        z0 += __bfloat162float(yv.h[0]);
        z1 += __bfloat162float(yv.h[1]);
        z2 += __bfloat162float(yv.h[2]);
        z3 += __bfloat162float(yv.h[3]);
    }

    float s = z0 + z1 + z2 + z3;
    float ss = z0 * z0 + z1 * z1 + z2 * z2 + z3 * z3;
#pragma unroll
    for (int off = 32; off > 0; off >>= 1) {
        s  += __shfl_down(s, off, 64);
        ss += __shfl_down(ss, off, 64);
    }
    __shared__ float red[4];
    int lane = tid & 63, wv = tid >> 6;
    if (lane == 0) { red[wv] = s; red[2 + wv] = ss; }
    __syncthreads();
    float S = red[0] + red[1];
    float SS = red[2] + red[3];
    float mu = S * (1.f / D_DIM);
    float var = SS * (1.f / D_DIM) - mu * mu;
    float inv = rsqrtf(var + 1e-5f);

    float4 gv = ((const float4*)gamma)[tid];
    float4 bv = ((const float4*)beta)[tid];
    float4 o;
    o.x = (z0 - mu) * inv * gv.x + bv.x;
    o.y = (z1 - mu) * inv * gv.y + bv.y;
    o.z = (z2 - mu) * inv * gv.z + bv.z;
    o.w = (z3 - mu) * inv * gv.w + bv.w;
    ((float4*)(out + (size_t)t * D_DIM))[tid] = o;
}

// ---------------------------------------------------------------------------
extern "C" void kernel_launch(void* const* d_in, const int* in_sizes, int n_in,
                              void* d_out, int out_size, void* d_ws, size_t ws_size,
                              hipStream_t stream)
{
    const float* x     = (const float*)d_in[0];
    const float* W1    = (const float*)d_in[1];
    const float* b1    = (const float*)d_in[2];
    const float* W2    = (const float*)d_in[3];
    const float* b2    = (const float*)d_in[4];
    const float* gamma = (const float*)d_in[5];
    const float* beta  = (const float*)d_in[6];
    const int* orig    = (const int*)d_in[7];
    const int* hmap    = (const int*)d_in[8];
    float* out = (float*)d_out;
    int ntok = in_sizes[7];   // B*S = 2048

    // Workspace layout (~21 MB)
    char* ws = (char*)d_ws;
    __hip_bfloat16* Yp  = (__hip_bfloat16*)(ws);             // [4][CAP][512] bf16, 10.49 MB
    __hip_bfloat16* Hb  = (__hip_bfloat16*)(ws + 10485760);  // [CAP][2048] bf16, 10.49 MB
    int*            gidx= (int*)(ws + 20971520);             // [CAP]
    int*            meta= (int*)(ws + 20981760);             // 32 ints

    hipLaunchKernelGGL(bin_kernel, dim3(1), dim3(256), 0, stream,
                       orig, hmap, gidx, meta, ntok);
    // GEMM1: x (fp32, gidx-indirect) x W1[E][512][2048] -> relu(+b1) -> bf16 Hb. grid 256.
    hipLaunchKernelGGL((moe_gemm_kernel<H_DIM, D_DIM, D_DIM, 1, true, true>),
                       dim3(H_DIM / 64, 1, E_NUM), dim3(256), 0, stream,
                       (const __hip_bfloat16*)nullptr, x, gidx, W1, b1,
                       Hb, (__hip_bfloat16*)nullptr, meta);
    // GEMM2: Hb[rows,2048] x W2[E][2048][512] -> bf16 partials (split-K=4). grid 256.
    hipLaunchKernelGGL((moe_gemm_kernel<D_DIM, H_DIM, H_DIM, 4, false, false>),
                       dim3(D_DIM / 64, 4, E_NUM), dim3(256), 0, stream,
                       Hb, (const float*)nullptr, (const int*)nullptr, W2,
                       (const float*)nullptr, (__hip_bfloat16*)nullptr, Yp, meta);
    hipLaunchKernelGGL(ln_kernel, dim3(CAP), dim3(128), 0, stream,
                       x, Yp, b2, gamma, beta, gidx, meta, out);
}

// Round 11
// 152.079 us; speedup vs baseline: 1.0713x; 1.0713x over previous
//
#include <hip/hip_runtime.h>
#include <hip/hip_bf16.h>
#include <stdint.h>

// Problem constants (fixed by reference): B=4,S=512 -> 2048 tokens, D=512, H=2048, E=8
#define D_DIM 512
#define H_DIM 2048
#define E_NUM 8
#define TM 64            // row-tile (padding granularity)
#define CAP 2560         // 2048 tokens + worst-case per-expert padding
#define MAXRT 6          // max row-tiles per expert (384 rows; ne~256±15, 8.5 sigma)

typedef __attribute__((ext_vector_type(8))) short short8;
typedef __attribute__((ext_vector_type(4))) float floatx4;

union Pack4 { short4 u; __hip_bfloat16 h[4]; };

// ---------------------------------------------------------------------------
// 1) Token binning. meta[0..7]=padded offset, [8..15]=ne, [16..23]=ntiles, [24]=total
__global__ __launch_bounds__(256) void bin_kernel(
    const int* __restrict__ orig, const int* __restrict__ hmap,
    int* __restrict__ gidx, int* __restrict__ meta, int ntok)
{
    __shared__ int cnt[E_NUM];
    __shared__ int cur[E_NUM];
    int tid = threadIdx.x;
    if (tid < E_NUM) cnt[tid] = 0;
    __syncthreads();
    for (int t = tid; t < ntok; t += 256) {
        int b = hmap[orig[t]];
        atomicAdd(&cnt[b], 1);
    }
    __syncthreads();
    if (tid == 0) {
        int off = 0;
        for (int e = 0; e < E_NUM; e++) {
            int ne = cnt[e];
            int nt = (ne + TM - 1) / TM;
            meta[e] = off; meta[8 + e] = ne; meta[16 + e] = nt;
            cur[e] = off;
            off += nt * TM;
        }
        meta[24] = off;
    }
    __syncthreads();
    for (int t = tid; t < ntok; t += 256) {
        int b = hmap[orig[t]];
        int p = atomicAdd(&cur[b], 1);
        gidx[p] = t;
    }
}

// ---------------------------------------------------------------------------
// 2) Gather x rows -> expert-sorted bf16 buffer; zero padding rows.
// (R10 fused this into gemm1 and regressed 9 µs: fp32 staging doubles bytes,
// scattered rows lose coalescing, +96 VGPR. Keep the separate gather.)
__global__ __launch_bounds__(128) void gather_kernel(
    const float* __restrict__ x, const int* __restrict__ gidx,
    const int* __restrict__ meta, __hip_bfloat16* __restrict__ Xg)
{
    int g = blockIdx.x;
    int e = -1, local = 0;
#pragma unroll
    for (int i = 0; i < E_NUM; i++) {
        int p = meta[i], nt = meta[16 + i];
        if (g >= p && g < p + nt * TM) { e = i; local = g - p; }
    }
    if (e < 0) return;
    int tid = threadIdx.x;
    __hip_bfloat16* orow = Xg + (size_t)g * D_DIM + tid * 4;
    if (local < meta[8 + e]) {
        int t = gidx[g];
        float4 v = ((const float4*)(x + (size_t)t * D_DIM))[tid];
        orow[0] = __float2bfloat16(v.x);
        orow[1] = __float2bfloat16(v.y);
        orow[2] = __float2bfloat16(v.z);
        orow[3] = __float2bfloat16(v.w);
    } else {
        orow[0] = __float2bfloat16(0.f);
        orow[1] = __float2bfloat16(0.f);
        orow[2] = __float2bfloat16(0.f);
        orow[3] = __float2bfloat16(0.f);
    }
}

// ---------------------------------------------------------------------------
// 3) Expert-column MoE GEMM (R9 champion). A staged via register round-trip
// (global->VGPR->ds_write): private vmem loads are NOT drained by
// __syncthreads (unlike global_load_lds DMA, which hits the compiler's
// vmcnt(0)-before-barrier rule), so A(i+1)/B(i+1) loads issued before
// compute(i) stay in flight across the barrier pair; their vmcnt wait lands
// at the ds_write one full iteration later -> latency hidden behind compute.
//   A  [CAP, ASTRIDE] bf16 expert-sorted;  W [E][KTOT][WN] fp32 (fused cvt+transpose)
//   RELU: OutBf = bf16(relu(acc + bias));  else OutP[ks][CAP][WN] bf16 partials
// LDS: As [384 x 64k] bf16 48 KB (phys chunk c=(row*8+q): byte c*16 holds
//      src k-bytes (q*16)^((row&7)*16) -> conflict-free b128 reads/writes),
//      Bs [64n x 64k] bf16 8 KB (phys(n,kb)=n*128+(kb^(((n>>2)&7)*16)))
template <int WN, int ASTRIDE, int KTOT, int KS, bool RELU>
__global__ __launch_bounds__(256) void moe_gemm_kernel(
    const __hip_bfloat16* __restrict__ A,
    const float* __restrict__ W,
    const float* __restrict__ bias,
    __hip_bfloat16* __restrict__ OutBf,   // RELU: full output
    __hip_bfloat16* __restrict__ OutP,    // !RELU: bf16 split-K partials
    const int* __restrict__ meta)
{
    constexpr int KLEN = KTOT / KS;           // 512 in both instantiations
    constexpr int NI = KLEN / 64;             // 8 k-iterations
    constexpr int AJ = MAXRT * 64 * 8 / 256;  // 12 A-chunks (16B) per thread max
    const int e = blockIdx.z;
    const int n0 = blockIdx.x * 64;
    const int ks = blockIdx.y;
    const int kbase = ks * KLEN;

    int nt = meta[16 + e];
    if (nt > MAXRT) nt = MAXRT;
    const int row0 = meta[e];
    const int rows8 = nt * 64 * 8;            // active 16B chunks in A stage

    __shared__ __align__(16) __hip_bfloat16 As[384 * 64];   // 48 KB
    __shared__ __align__(16) __hip_bfloat16 Bs[64 * 64];    // 8 KB

    const int tid = threadIdx.x;
    const int lane = tid & 63, w = tid >> 6;
    const int quad = lane >> 4, l16 = lane & 15;
    const int wr = w >> 1, wc = w & 1;        // 2x2 wave grid per 64x64 tile
    const int kq = tid >> 4;                  // B staging: 4 k-rows
    const int nb = tid & 15;                  // B staging: 4 n-cols

    const __hip_bfloat16* Ab = A + (size_t)row0 * ASTRIDE + kbase;
    const float* Wb = W + ((size_t)e * KTOT + kbase) * WN + n0;

    floatx4 acc[MAXRT][2][2] = {};
    short8 ar[AJ];    // A prefetch registers (48 VGPRs)
    float4 br[4];     // B prefetch registers (16 VGPRs)

#define LOADA(k0) do {                                                        \
    _Pragma("unroll")                                                         \
    for (int j = 0; j < AJ; j++) {                                            \
        int c = tid + j * 256;                                                \
        if (c < rows8) {                                                      \
            int row = c >> 3;                                                 \
            int kk = ((c & 7) * 16) ^ ((row & 7) * 16);   /* bytes */         \
            ar[j] = *(const short8*)(Ab + (size_t)row * ASTRIDE + (k0) + (kk >> 1)); \
        }                                                                     \
    }                                                                         \
} while (0)

#define WRITEA() do {                                                         \
    _Pragma("unroll")                                                         \
    for (int j = 0; j < AJ; j++) {                                            \
        int c = tid + j * 256;                                                \
        if (c < rows8)                                                        \
            *(short8*)((char*)As + c * 16) = ar[j];                           \
    }                                                                         \
} while (0)

#define LOADB(k0) do {                                                        \
    _Pragma("unroll")                                                         \
    for (int r = 0; r < 4; r++)                                               \
        br[r] = *(const float4*)(Wb + (size_t)((k0) + kq * 4 + r) * WN + nb * 4); \
} while (0)

#define WRITEB() do {                                                         \
    _Pragma("unroll")                                                         \
    for (int j = 0; j < 4; j++) {                                             \
        int n = nb * 4 + j;                                                   \
        Pack4 pk;                                                             \
        _Pragma("unroll")                                                     \
        for (int r = 0; r < 4; r++)                                           \
            pk.h[r] = __float2bfloat16(reinterpret_cast<const float*>(&br[r])[j]); \
        *(short4*)((char*)Bs + n * 128 + ((kq * 8) ^ (((n >> 2) & 7) * 16))) = pk.u; \
    }                                                                         \
} while (0)

    LOADA(0);
    LOADB(0);

    for (int i = 0; i < NI; i++) {
        __syncthreads();    // prior iter's LDS reads complete
        WRITEA();           // vmcnt wait for loads issued one iter ago lands here
        WRITEB();
        __syncthreads();
        if (i + 1 < NI) {   // issue next-iter loads; they fly across the barriers
            LOADA((i + 1) * 64);
            LOADB((i + 1) * 64);
        }
#pragma unroll
        for (int kf = 0; kf < 2; kf++) {
            int kb = kf * 64 + quad * 16;
            short8 b[2];
#pragma unroll
            for (int ni = 0; ni < 2; ni++) {
                int n = wc * 32 + ni * 16 + l16;
                b[ni] = *(const short8*)((char*)Bs + n * 128 + (kb ^ (((n >> 2) & 7) * 16)));
            }
#pragma unroll
            for (int rt = 0; rt < MAXRT; rt++) {
                if (rt < nt) {
                    short8 a[2];
#pragma unroll
                    for (int mi = 0; mi < 2; mi++) {
                        int row = rt * 64 + wr * 32 + mi * 16 + l16;
                        a[mi] = *(const short8*)((char*)As + row * 128 + (kb ^ ((row & 7) * 16)));
                    }
#pragma unroll
                    for (int mi = 0; mi < 2; mi++)
#pragma unroll
                        for (int ni = 0; ni < 2; ni++)
                            acc[rt][mi][ni] = __builtin_amdgcn_mfma_f32_16x16x32_bf16(
                                a[mi], b[ni], acc[rt][mi][ni], 0, 0, 0);
                }
            }
        }
    }

    // Epilogue. C/D layout (m89-verified): col = lane&15, row = (lane>>4)*4 + reg
#pragma unroll
    for (int rt = 0; rt < MAXRT; rt++) {
        if (rt >= nt) break;
#pragma unroll
        for (int ni = 0; ni < 2; ni++) {
            int col = n0 + wc * 32 + ni * 16 + l16;
            float bv = RELU ? bias[e * WN + col] : 0.f;
#pragma unroll
            for (int mi = 0; mi < 2; mi++) {
#pragma unroll
                for (int r = 0; r < 4; r++) {
                    int grow = row0 + rt * 64 + wr * 32 + mi * 16 + quad * 4 + r;
                    float v = acc[rt][mi][ni][r] + bv;
                    if constexpr (RELU) {
                        v = v > 0.f ? v : 0.f;
                        OutBf[(size_t)grow * WN + col] = __float2bfloat16(v);
                    } else {
                        OutP[((size_t)ks * CAP + grow) * WN + col] = __float2bfloat16(v);
                    }
                }
            }
        }
    }
#undef LOADA
#undef WRITEA
#undef LOADB
#undef WRITEB
}

// ---------------------------------------------------------------------------
// 4) Residual + b2 + 4-way bf16 split-K sum + LayerNorm, scatter to token order.
__global__ __launch_bounds__(128) void ln_kernel(
    const float* __restrict__ x, const __hip_bfloat16* __restrict__ Yp,
    const float* __restrict__ b2,
    const float* __restrict__ gamma, const float* __restrict__ beta,
    const int* __restrict__ gidx, const int* __restrict__ meta,
    float* __restrict__ out)
{
    int g = blockIdx.x;
    int e = -1;
#pragma unroll
    for (int i = 0; i < E_NUM; i++) {
        int p = meta[i], ne = meta[8 + i];
        if (g >= p && g - p < ne) e = i;
    }
    if (e < 0) return;   // padding row or beyond total
    int t = gidx[g];
    int tid = threadIdx.x;

    float4 xv = ((const float4*)(x + (size_t)t * D_DIM))[tid];
    float4 bb = ((const float4*)(b2 + (size_t)e * D_DIM))[tid];
    float z0 = xv.x + bb.x, z1 = xv.y + bb.y, z2 = xv.z + bb.z, z3 = xv.w + bb.w;
#pragma unroll
    for (int s4 = 0; s4 < 4; s4++) {
        union { short4 u; __hip_bfloat16 h[4]; } yv;
        yv.u = ((const short4*)(Yp + (size_t)(s4 * CAP + g) * D_DIM))[tid];
        z0 += __bfloat162float(yv.h[0]);
        z1 += __bfloat162float(yv.h[1]);
        z2 += __bfloat162float(yv.h[2]);
        z3 += __bfloat162float(yv.h[3]);
    }

    float s = z0 + z1 + z2 + z3;
    float ss = z0 * z0 + z1 * z1 + z2 * z2 + z3 * z3;
#pragma unroll
    for (int off = 32; off > 0; off >>= 1) {
        s  += __shfl_down(s, off, 64);
        ss += __shfl_down(ss, off, 64);
    }
    __shared__ float red[4];
    int lane = tid & 63, wv = tid >> 6;
    if (lane == 0) { red[wv] = s; red[2 + wv] = ss; }
    __syncthreads();
    float S = red[0] + red[1];
    float SS = red[2] + red[3];
    float mu = S * (1.f / D_DIM);
    float var = SS * (1.f / D_DIM) - mu * mu;
    float inv = rsqrtf(var + 1e-5f);

    float4 gv = ((const float4*)gamma)[tid];
    float4 bv = ((const float4*)beta)[tid];
    float4 o;
    o.x = (z0 - mu) * inv * gv.x + bv.x;
    o.y = (z1 - mu) * inv * gv.y + bv.y;
    o.z = (z2 - mu) * inv * gv.z + bv.z;
    o.w = (z3 - mu) * inv * gv.w + bv.w;
    ((float4*)(out + (size_t)t * D_DIM))[tid] = o;
}

// ---------------------------------------------------------------------------
extern "C" void kernel_launch(void* const* d_in, const int* in_sizes, int n_in,
                              void* d_out, int out_size, void* d_ws, size_t ws_size,
                              hipStream_t stream)
{
    const float* x     = (const float*)d_in[0];
    const float* W1    = (const float*)d_in[1];
    const float* b1    = (const float*)d_in[2];
    const float* W2    = (const float*)d_in[3];
    const float* b2    = (const float*)d_in[4];
    const float* gamma = (const float*)d_in[5];
    const float* beta  = (const float*)d_in[6];
    const int* orig    = (const int*)d_in[7];
    const int* hmap    = (const int*)d_in[8];
    float* out = (float*)d_out;
    int ntok = in_sizes[7];   // B*S = 2048

    // Workspace layout (~23.6 MB)
    char* ws = (char*)d_ws;
    __hip_bfloat16* Yp  = (__hip_bfloat16*)(ws);             // [4][CAP][512] bf16, 10.49 MB
    __hip_bfloat16* Hb  = (__hip_bfloat16*)(ws + 10485760);  // [CAP][2048] bf16, 10.49 MB
    __hip_bfloat16* Xg  = (__hip_bfloat16*)(ws + 20971520);  // [CAP][512] bf16, 2.62 MB
    int*            gidx= (int*)(ws + 23592960);             // [CAP]
    int*            meta= (int*)(ws + 23603200);             // 32 ints

    hipLaunchKernelGGL(bin_kernel, dim3(1), dim3(256), 0, stream,
                       orig, hmap, gidx, meta, ntok);
    hipLaunchKernelGGL(gather_kernel, dim3(CAP), dim3(128), 0, stream,
                       x, gidx, meta, Xg);
    // GEMM1: Xg[rows,512] x W1[E][512][2048] -> relu(+b1) -> bf16 Hb. grid 256.
    hipLaunchKernelGGL((moe_gemm_kernel<H_DIM, D_DIM, D_DIM, 1, true>),
                       dim3(H_DIM / 64, 1, E_NUM), dim3(256), 0, stream,
                       Xg, W1, b1, Hb, (__hip_bfloat16*)nullptr, meta);
    // GEMM2: Hb[rows,2048] x W2[E][2048][512] -> bf16 partials (split-K=4). grid 256.
    hipLaunchKernelGGL((moe_gemm_kernel<D_DIM, H_DIM, H_DIM, 4, false>),
                       dim3(D_DIM / 64, 4, E_NUM), dim3(256), 0, stream,
                       Hb, W2, (const float*)nullptr, (__hip_bfloat16*)nullptr, Yp, meta);
    hipLaunchKernelGGL(ln_kernel, dim3(CAP), dim3(128), 0, stream,
                       x, Yp, b2, gamma, beta, gidx, meta, out);
}